// Round 3
// baseline (263.709 us; speedup 1.0000x reference)
//
#include <hip/hip_runtime.h>
#include <hip/hip_bf16.h>

typedef unsigned short u16;
typedef unsigned int   u32;
using short8   = __attribute__((ext_vector_type(8))) short;
using f32x4    = __attribute__((ext_vector_type(4))) float;
using u32x4    = __attribute__((ext_vector_type(4))) unsigned int;

#define CDIM 256
#define LDIM 16384
#define LT   128
#define NT   128   // L tiles per batch
#define NB   8

__device__ __forceinline__ u16 f2bf(float f) {
  u32 u = __float_as_uint(f);
  u = (u + 0x7FFFu + ((u >> 16) & 1u)) >> 16;   // RTNE
  return (u16)u;
}

__device__ __forceinline__ u32 pk2(float a, float b) {
  __hip_bfloat162 h = __float22bfloat162_rn(make_float2(a, b));  // a -> low
  return *(u32*)&h;
}

// LDS image: byte(l,c) = l*512 + slot*16 + (c&7)*2,
//            slot = (c>>3) ^ ((l>>2)&31) ^ ((l&3)<<2)
__device__ __forceinline__ int swz(int l) {
  return ((l >> 2) & 31) ^ ((l & 3) << 2);
}

__device__ __forceinline__ short8 frag_b(const char* xl, int ll, int kk, int g) {
  int slot = (kk * 4 + g) ^ swz(ll);
  return *(const short8*)(xl + (size_t)ll * 512 + slot * 16);
}

// ---------------- prep: weight bf16 conversion, wvsum, bilinear upsample ----
__global__ void k_prep(const float* __restrict__ wq_x, const float* __restrict__ wk_x,
                       const float* __restrict__ w_out, const float* __restrict__ wv,
                       const float* __restrict__ y,
                       u16* __restrict__ wqx_bf, u16* __restrict__ wkx_bf,
                       u16* __restrict__ wout_bf, u16* __restrict__ wvsum_bf,
                       float* __restrict__ yup) {
  int id = blockIdx.x * 256 + threadIdx.x;
  if (id < 65536) {
    wqx_bf[id]  = f2bf(wq_x[id]);
    wkx_bf[id]  = f2bf(wk_x[id]);
    wout_bf[id] = f2bf(w_out[id]);
  }
  if (id < 4096) {  // wvsum padded to 16 rows (rows 8..15 zero)
    int r = id >> 8, c = id & 255;
    float s = 0.f;
    if (r < 8) {
      for (int d2 = 0; d2 < 32; ++d2) s += wv[(r * 32 + d2) * 256 + c];
    }
    wvsum_bf[id] = f2bf(s);
  }
  if (id < 131072) {  // bilinear 2x upsample, half-pixel (align_corners=False)
    int b = id >> 14, rem = id & 16383, i = rem >> 7, j = rem & 127;
    float si = 0.5f * i - 0.25f, sj = 0.5f * j - 0.25f;
    int i0 = (int)floorf(si), j0 = (int)floorf(sj);
    float fi = si - (float)i0, fj = sj - (float)j0;
    int i0c = i0 < 0 ? 0 : i0, i1c = i0 + 1 > 63 ? 63 : i0 + 1;
    int j0c = j0 < 0 ? 0 : j0, j1c = j0 + 1 > 63 ? 63 : j0 + 1;
    const float* yb = y + b * 4096;
    float v = (1.f - fi) * ((1.f - fj) * yb[i0c * 64 + j0c] + fj * yb[i0c * 64 + j1c])
            +        fi  * ((1.f - fj) * yb[i1c * 64 + j0c] + fj * yb[i1c * 64 + j1c]);
    yup[id] = v;
  }
}

// ---------------- staging: x f32 -> swizzled LDS bf16 image ------------------
// 512 threads. lanes 0..31 of each wave span l contiguously -> coalesced loads.
__device__ __forceinline__ void stage_x(char* xl, const float* __restrict__ x,
                                        int b, int l0, int tid) {
  int k = tid & 31, cg = tid >> 5;   // l-chunk (4 l's), c-octet group (0..15)
  const float* bp = x + ((size_t)b * 256 + cg * 8) * LDIM + l0 + k * 4;
#pragma unroll
  for (int it = 0; it < 2; ++it) {
    const float* p = bp + (size_t)(128 * it) * LDIM;
    float4 r0 = *(const float4*)(p + 0 * LDIM);
    float4 r1 = *(const float4*)(p + 1 * LDIM);
    float4 r2 = *(const float4*)(p + 2 * LDIM);
    float4 r3 = *(const float4*)(p + 3 * LDIM);
    float4 r4 = *(const float4*)(p + 4 * LDIM);
    float4 r5 = *(const float4*)(p + 5 * LDIM);
    float4 r6 = *(const float4*)(p + 6 * LDIM);
    float4 r7 = *(const float4*)(p + 7 * LDIM);
    int sl = cg + 16 * it;
    const float* f0 = (const float*)&r0; const float* f1 = (const float*)&r1;
    const float* f2 = (const float*)&r2; const float* f3 = (const float*)&r3;
    const float* f4 = (const float*)&r4; const float* f5 = (const float*)&r5;
    const float* f6 = (const float*)&r6; const float* f7 = (const float*)&r7;
#pragma unroll
    for (int e = 0; e < 4; ++e) {
      int l = k * 4 + e;
      u32x4 wv;
      wv.x = pk2(f0[e], f1[e]);
      wv.y = pk2(f2[e], f3[e]);
      wv.z = pk2(f4[e], f5[e]);
      wv.w = pk2(f6[e], f7[e]);
      int slot = sl ^ swz(l);
      *(u32x4*)(xl + (size_t)l * 512 + slot * 16) = wv;
    }
  }
}

// ---------------- pass 1: ksum / kvs partials ---------------------------------
__global__ __launch_bounds__(512, 4) void k_pass1(
    const float* __restrict__ x, const u16* __restrict__ wkx_bf,
    const u16* __restrict__ wvsum_bf, const float* __restrict__ wk_y,
    const float* __restrict__ yup, float* __restrict__ part) {
  __shared__ u32x4 xbuf[4096];            // 64 KB
  __shared__ float vsum_lds[8 * 128];     // [head][l]
  __shared__ float yup_lds[128];
  __shared__ float wky_lds[256];
  char* xl = (char*)xbuf;

  int tid = threadIdx.x, bid = blockIdx.x;
  int b = bid >> 7, tile = bid & 127;
  int l0 = tile * LT;

  if (tid < 128) yup_lds[tid] = yup[b * LDIM + l0 + tid];
  if (tid < 256) wky_lds[tid] = wk_y[tid];
  stage_x(xl, x, b, l0, tid);
  __syncthreads();

  int lane = tid & 63, w = tid >> 6;      // 8 waves
  int lid = lane & 15, g = lane >> 4;
  int wb = w * 32;                        // wave covers head w (c = wb..wb+31)

  f32x4 z4 = {0.f, 0.f, 0.f, 0.f};
  f32x4 acc[2][8];
#pragma unroll
  for (int i = 0; i < 2; ++i)
#pragma unroll
    for (int j = 0; j < 8; ++j) acc[i][j] = z4;
  f32x4 vacc = z4;

  for (int kk = 0; kk < 8; ++kk) {
    int kof = kk * 32 + g * 8;
    short8 a0 = *(const short8*)(wkx_bf + (size_t)(wb + lid) * 256 + kof);
    short8 a1 = *(const short8*)(wkx_bf + (size_t)(wb + 16 + lid) * 256 + kof);
    short8 av = *(const short8*)(wvsum_bf + (size_t)lid * 256 + kof);
#pragma unroll
    for (int fn = 0; fn < 8; ++fn) {
      short8 bb = frag_b(xl, fn * 16 + lid, kk, g);
      acc[0][fn] = __builtin_amdgcn_mfma_f32_16x16x32_bf16(a0, bb, acc[0][fn], 0, 0, 0);
      acc[1][fn] = __builtin_amdgcn_mfma_f32_16x16x32_bf16(a1, bb, acc[1][fn], 0, 0, 0);
    }
    // vsum mini-GEMM: this wave covers l-block fn = w
    short8 bv = frag_b(xl, w * 16 + lid, kk, g);
    vacc = __builtin_amdgcn_mfma_f32_16x16x32_bf16(av, bv, vacc, 0, 0, 0);
  }
  // scatter vsum: D row = head h = g*4+r (real h<8 -> g<2), col l = w*16+lid
  if (g < 2) {
#pragma unroll
    for (int r = 0; r < 4; ++r)
      vsum_lds[(g * 4 + r) * 128 + w * 16 + lid] = vacc[r];
  }
  __syncthreads();

  float wky_r[2][4];
#pragma unroll
  for (int fm = 0; fm < 2; ++fm)
#pragma unroll
    for (int r = 0; r < 4; ++r) wky_r[fm][r] = wky_lds[wb + fm * 16 + g * 4 + r];

  float s1[2][4], s2[2][4];
#pragma unroll
  for (int fm = 0; fm < 2; ++fm)
#pragma unroll
    for (int r = 0; r < 4; ++r) { s1[fm][r] = 0.f; s2[fm][r] = 0.f; }

#pragma unroll
  for (int fn = 0; fn < 8; ++fn) {
    int l = fn * 16 + lid;
    float yv = yup_lds[l];
    float vs = vsum_lds[w * 128 + l];     // head w
#pragma unroll
    for (int fm = 0; fm < 2; ++fm)
#pragma unroll
      for (int r = 0; r < 4; ++r) {
        float v = acc[fm][fn][r] * (wky_r[fm][r] * yv);
        float kq = v > 0.f ? v + 1.f : __expf(v);   // elu(v)+1
        s1[fm][r] += kq;
        s2[fm][r] += kq * vs;
      }
  }
#pragma unroll
  for (int fm = 0; fm < 2; ++fm)
#pragma unroll
    for (int r = 0; r < 4; ++r) {
      float a1 = s1[fm][r], a2 = s2[fm][r];
#pragma unroll
      for (int off = 1; off < 16; off <<= 1) {
        a1 += __shfl_xor(a1, off);
        a2 += __shfl_xor(a2, off);
      }
      if (lid == 0) {
        int c = wb + fm * 16 + g * 4 + r;
        part[(size_t)bid * 512 + c]       = a1;
        part[(size_t)bid * 512 + 256 + c] = a2;
      }
    }
}

// ---------------- reduce partials -> ksum, kvs --------------------------------
__global__ __launch_bounds__(1024) void k_reduce(
    const float* __restrict__ part, float* __restrict__ ksum, float* __restrict__ kvs) {
  __shared__ float red[2][512];
  int b = blockIdx.x, tid = threadIdx.x;
  int u = tid & 511, h = tid >> 9;
  float s = 0.f;
  for (int j = 0; j < 64; ++j)
    s += part[(size_t)(b * NT + h * 64 + j) * 512 + u];
  red[h][u] = s;
  __syncthreads();
  if (tid < 512) {
    float t = red[0][tid] + red[1][tid];
    if (tid < 256) ksum[b * 256 + tid] = t;
    else           kvs[b * 256 + tid - 256] = t;
  }
}

// ---------------- pass 2: q, z, t, w_out GEMM, output -------------------------
__global__ __launch_bounds__(512, 4) void k_pass2(
    const float* __restrict__ x, const u16* __restrict__ wqx_bf,
    const u16* __restrict__ wout_bf, const float* __restrict__ wq_y,
    const float* __restrict__ yup, const float* __restrict__ ksum,
    const float* __restrict__ kvs, const float* __restrict__ b_out,
    float* __restrict__ out) {
  __shared__ u32x4 xbuf[4096];            // 64 KB
  __shared__ float yup_lds[128];
  __shared__ float wqy_lds[256];
  __shared__ float ksum_lds[256];
  __shared__ float kvs_lds[256];
  __shared__ float bout_lds[256];
  char* xl = (char*)xbuf;

  int tid = threadIdx.x, bid = blockIdx.x;
  int b = bid >> 7, tile = bid & 127;
  int l0 = tile * LT;

  if (tid < 128) yup_lds[tid] = yup[b * LDIM + l0 + tid];
  if (tid < 256) {
    wqy_lds[tid]  = wq_y[tid];
    ksum_lds[tid] = ksum[b * 256 + tid];
    kvs_lds[tid]  = kvs[b * 256 + tid];
    bout_lds[tid] = b_out[tid];
  }
  stage_x(xl, x, b, l0, tid);
  __syncthreads();

  int lane = tid & 63, w = tid >> 6;
  int lid = lane & 15, g = lane >> 4;
  int wb = w * 32;

  f32x4 z4 = {0.f, 0.f, 0.f, 0.f};
  f32x4 acc[2][8];
#pragma unroll
  for (int i = 0; i < 2; ++i)
#pragma unroll
    for (int j = 0; j < 8; ++j) acc[i][j] = z4;

  // GEMM1: q_x = wq_x * x
  for (int kk = 0; kk < 8; ++kk) {
    int kof = kk * 32 + g * 8;
    short8 a0 = *(const short8*)(wqx_bf + (size_t)(wb + lid) * 256 + kof);
    short8 a1 = *(const short8*)(wqx_bf + (size_t)(wb + 16 + lid) * 256 + kof);
#pragma unroll
    for (int fn = 0; fn < 8; ++fn) {
      short8 bb = frag_b(xl, fn * 16 + lid, kk, g);
      acc[0][fn] = __builtin_amdgcn_mfma_f32_16x16x32_bf16(a0, bb, acc[0][fn], 0, 0, 0);
      acc[1][fn] = __builtin_amdgcn_mfma_f32_16x16x32_bf16(a1, bb, acc[1][fn], 0, 0, 0);
    }
  }
  __syncthreads();  // x_lds reads done; buffer reused for t

  float wqy_r[2][4], ks_r[2][4], kv_r[2][4];
#pragma unroll
  for (int fm = 0; fm < 2; ++fm)
#pragma unroll
    for (int r = 0; r < 4; ++r) {
      int c = wb + fm * 16 + g * 4 + r;
      wqy_r[fm][r] = wqy_lds[c];
      ks_r[fm][r]  = ksum_lds[c];
      kv_r[fm][r]  = kvs_lds[c];
    }

#pragma unroll
  for (int fn = 0; fn < 8; ++fn) {
    int l = fn * 16 + lid;
    float yv = yup_lds[l];
    float q[2][4];
    float d = 0.f;
#pragma unroll
    for (int fm = 0; fm < 2; ++fm)
#pragma unroll
      for (int r = 0; r < 4; ++r) {
        float v = acc[fm][fn][r] * (wqy_r[fm][r] * yv);
        float qq = v > 0.f ? v + 1.f : __expf(v);   // elu(v)+1
        q[fm][r] = qq;
        d += qq * ks_r[fm][r];
      }
    d += __shfl_xor(d, 16); d += __shfl_xor(d, 32);   // sum over g: all 32 c of head w
    float zz = 1.f / (d + 1e-6f);
    // t image write (same swizzled layout)
    int sl = w * 4 + (g >> 1);           // (c>>3) with c-octet base; fm adds 2
#pragma unroll
    for (int fm = 0; fm < 2; ++fm) {
      u32 w0 = pk2(q[fm][0] * kv_r[fm][0] * zz, q[fm][1] * kv_r[fm][1] * zz);
      u32 w1 = pk2(q[fm][2] * kv_r[fm][2] * zz, q[fm][3] * kv_r[fm][3] * zz);
      int slot = (sl + fm * 2) ^ swz(l);
      char* p = xl + (size_t)l * 512 + slot * 16 + (g & 1) * 8;
      *(u32*)p = w0;
      *(u32*)(p + 4) = w1;
    }
  }
  __syncthreads();

  // GEMM2: out = w_out * t
#pragma unroll
  for (int i = 0; i < 2; ++i)
#pragma unroll
    for (int j = 0; j < 8; ++j) acc[i][j] = z4;
  for (int kk = 0; kk < 8; ++kk) {
    int kof = kk * 32 + g * 8;
    short8 a0 = *(const short8*)(wout_bf + (size_t)(wb + lid) * 256 + kof);
    short8 a1 = *(const short8*)(wout_bf + (size_t)(wb + 16 + lid) * 256 + kof);
#pragma unroll
    for (int fn = 0; fn < 8; ++fn) {
      short8 bb = frag_b(xl, fn * 16 + lid, kk, g);
      acc[0][fn] = __builtin_amdgcn_mfma_f32_16x16x32_bf16(a0, bb, acc[0][fn], 0, 0, 0);
      acc[1][fn] = __builtin_amdgcn_mfma_f32_16x16x32_bf16(a1, bb, acc[1][fn], 0, 0, 0);
    }
  }

  // epilogue
#pragma unroll
  for (int fm = 0; fm < 2; ++fm) {
#pragma unroll
    for (int r = 0; r < 4; ++r) {
      int o = wb + fm * 16 + g * 4 + r;
      float bo = bout_lds[o];
      size_t base = ((size_t)b * 256 + o) * LDIM + l0;
#pragma unroll
      for (int fn = 0; fn < 8; ++fn)
        out[base + fn * 16 + lid] = acc[fm][fn][r] + bo;
    }
  }
}

// ---------------- launch -------------------------------------------------------
extern "C" void kernel_launch(void* const* d_in, const int* in_sizes, int n_in,
                              void* d_out, int out_size, void* d_ws, size_t ws_size,
                              hipStream_t stream) {
  const float* x     = (const float*)d_in[0];
  const float* y     = (const float*)d_in[1];
  const float* wq_x  = (const float*)d_in[2];
  const float* wk_x  = (const float*)d_in[3];
  const float* wv    = (const float*)d_in[4];
  const float* wq_y  = (const float*)d_in[5];
  const float* wk_y  = (const float*)d_in[6];
  const float* w_out = (const float*)d_in[7];
  const float* b_out = (const float*)d_in[8];
  float* out = (float*)d_out;

  char* ws = (char*)d_ws;
  float* yup      = (float*)(ws + 0);         // 512 KB
  u16*   wqx_bf   = (u16*)(ws + 524288);      // 128 KB
  u16*   wkx_bf   = (u16*)(ws + 655360);      // 128 KB
  u16*   wout_bf  = (u16*)(ws + 786432);      // 128 KB
  u16*   wvsum_bf = (u16*)(ws + 917504);      // 8 KB
  float* ksum     = (float*)(ws + 925696);    // 8 KB
  float* kvs      = (float*)(ws + 933888);    // 8 KB
  float* part     = (float*)(ws + 942080);    // 2 MB

  k_prep<<<512, 256, 0, stream>>>(wq_x, wk_x, w_out, wv, y,
                                  wqx_bf, wkx_bf, wout_bf, wvsum_bf, yup);
  k_pass1<<<NB * NT, 512, 0, stream>>>(x, wkx_bf, wvsum_bf, wk_y, yup, part);
  k_reduce<<<NB, 1024, 0, stream>>>(part, ksum, kvs);
  k_pass2<<<NB * NT, 512, 0, stream>>>(x, wqx_bf, wout_bf, wq_y, yup,
                                       ksum, kvs, b_out, out);
}

// Round 4
// 152.983 us; speedup vs baseline: 1.7238x; 1.7238x over previous
//
#include <hip/hip_runtime.h>
#include <hip/hip_bf16.h>

typedef unsigned short u16;
typedef unsigned int   u32;
using short8   = __attribute__((ext_vector_type(8))) short;
using f32x4    = __attribute__((ext_vector_type(4))) float;
using ushort4v = __attribute__((ext_vector_type(4))) unsigned short;
using u32x4    = __attribute__((ext_vector_type(4))) unsigned int;

#define CDIM 256
#define LDIM 16384
#define LT   128
#define NT   128   // L tiles per batch
#define NB   8

__device__ __forceinline__ u16 f2bf(float f) {
  u32 u = __float_as_uint(f);
  u = (u + 0x7FFFu + ((u >> 16) & 1u)) >> 16;   // RTNE
  return (u16)u;
}

__device__ __forceinline__ u32 pk2(float a, float b) {
  __hip_bfloat162 h = __float22bfloat162_rn(make_float2(a, b));  // a -> low
  return *(u32*)&h;
}

// LDS image: byte(l,c) = l*512 + slot*16 + (c&7)*2,
//            slot = (c>>3) ^ swz(l),  swz(l) = ((l>>2)&31) ^ ((l&3)<<2)
__device__ __forceinline__ int swz(int l) {
  return ((l >> 2) & 31) ^ ((l & 3) << 2);
}

// B-fragment read: rows ll, k-slice = kk*32 + g*8 .. +7  (c-octet = kk*4+g)
__device__ __forceinline__ short8 frag_b(const char* xl, int ll, int kk, int g) {
  int slot = (kk * 4 + g) ^ swz(ll);
  return *(const short8*)(xl + (size_t)ll * 512 + slot * 16);
}

// ---------------- prep: weight bf16 conversion, wvsum, bilinear upsample ----
__global__ void k_prep(const float* __restrict__ wq_x, const float* __restrict__ wk_x,
                       const float* __restrict__ w_out, const float* __restrict__ wv,
                       const float* __restrict__ y,
                       u16* __restrict__ wqx_bf, u16* __restrict__ wkx_bf,
                       u16* __restrict__ wout_bf, u16* __restrict__ wvsum_bf,
                       float* __restrict__ yup) {
  int id = blockIdx.x * 256 + threadIdx.x;
  if (id < 65536) {
    wqx_bf[id]  = f2bf(wq_x[id]);
    wkx_bf[id]  = f2bf(wk_x[id]);
    wout_bf[id] = f2bf(w_out[id]);
  }
  if (id < 4096) {  // wvsum padded to 16 rows (rows 8..15 zero)
    int r = id >> 8, c = id & 255;
    float s = 0.f;
    if (r < 8) {
      for (int d2 = 0; d2 < 32; ++d2) s += wv[(r * 32 + d2) * 256 + c];
    }
    wvsum_bf[id] = f2bf(s);
  }
  if (id < 131072) {  // bilinear 2x upsample, half-pixel (align_corners=False)
    int b = id >> 14, rem = id & 16383, i = rem >> 7, j = rem & 127;
    float si = 0.5f * i - 0.25f, sj = 0.5f * j - 0.25f;
    int i0 = (int)floorf(si), j0 = (int)floorf(sj);
    float fi = si - (float)i0, fj = sj - (float)j0;
    int i0c = i0 < 0 ? 0 : i0, i1c = i0 + 1 > 63 ? 63 : i0 + 1;
    int j0c = j0 < 0 ? 0 : j0, j1c = j0 + 1 > 63 ? 63 : j0 + 1;
    const float* yb = y + b * 4096;
    float v = (1.f - fi) * ((1.f - fj) * yb[i0c * 64 + j0c] + fj * yb[i0c * 64 + j1c])
            +        fi  * ((1.f - fj) * yb[i1c * 64 + j0c] + fj * yb[i1c * 64 + j1c]);
    yup[id] = v;
  }
}

// ---------------- staging: x f32 -> swizzled LDS bf16 image, 256 threads -----
// lane k = tid&31 spans l contiguously -> each load inst covers 2x512B runs.
__device__ __forceinline__ void stage_x(char* xl, const float* __restrict__ x,
                                        int b, int l0, int tid) {
  int k = tid & 31, co = tid >> 5;   // l-chunk (4 l's), base c-octet (0..7)
  const float* bp = x + ((size_t)b * 256 + co * 8) * LDIM + l0 + k * 4;
#pragma unroll
  for (int oi = 0; oi < 4; ++oi) {
    const float* p = bp + (size_t)(oi * 64) * LDIM;   // octet o = co + oi*8
    float4 r0 = *(const float4*)(p + 0 * LDIM);
    float4 r1 = *(const float4*)(p + 1 * LDIM);
    float4 r2 = *(const float4*)(p + 2 * LDIM);
    float4 r3 = *(const float4*)(p + 3 * LDIM);
    float4 r4 = *(const float4*)(p + 4 * LDIM);
    float4 r5 = *(const float4*)(p + 5 * LDIM);
    float4 r6 = *(const float4*)(p + 6 * LDIM);
    float4 r7 = *(const float4*)(p + 7 * LDIM);
    const float* f0 = (const float*)&r0; const float* f1 = (const float*)&r1;
    const float* f2 = (const float*)&r2; const float* f3 = (const float*)&r3;
    const float* f4 = (const float*)&r4; const float* f5 = (const float*)&r5;
    const float* f6 = (const float*)&r6; const float* f7 = (const float*)&r7;
    int so = co + oi * 8;
#pragma unroll
    for (int e = 0; e < 4; ++e) {
      int l = k * 4 + e;
      u32x4 wv;
      wv.x = pk2(f0[e], f1[e]);
      wv.y = pk2(f2[e], f3[e]);
      wv.z = pk2(f4[e], f5[e]);
      wv.w = pk2(f6[e], f7[e]);
      int slot = so ^ swz(l);
      *(u32x4*)(xl + (size_t)l * 512 + slot * 16) = wv;
    }
  }
}

// ---------------- pass 1: ksum / kvs partials ---------------------------------
__global__ __launch_bounds__(256, 2) void k_pass1(
    const float* __restrict__ x, const u16* __restrict__ wkx_bf,
    const u16* __restrict__ wvsum_bf, const float* __restrict__ wk_y,
    const float* __restrict__ yup, float* __restrict__ part) {
  __shared__ u32x4 xbuf[4096];            // 64 KB
  __shared__ float vsum_lds[8 * 128];     // [head][l]
  __shared__ float yup_lds[128];
  __shared__ float wky_lds[256];
  char* xl = (char*)xbuf;

  int tid = threadIdx.x, bid = blockIdx.x;
  int b = bid >> 7, tile = bid & 127;
  int l0 = tile * LT;

  if (tid < 128) yup_lds[tid] = yup[b * LDIM + l0 + tid];
  wky_lds[tid] = wk_y[tid];
  stage_x(xl, x, b, l0, tid);
  __syncthreads();

  int lane = tid & 63, wave = tid >> 6;
  int lid = lane & 15, g = lane >> 4;
  int wb = wave * 64;

  f32x4 z4 = {0.f, 0.f, 0.f, 0.f};
  f32x4 acc[4][8];
#pragma unroll
  for (int i = 0; i < 4; ++i)
#pragma unroll
    for (int j = 0; j < 8; ++j) acc[i][j] = z4;
  f32x4 vacc[2] = {z4, z4};

  for (int kk = 0; kk < 8; ++kk) {
    int kof = kk * 32 + g * 8;
    short8 a[4];
#pragma unroll
    for (int fm = 0; fm < 4; ++fm)
      a[fm] = *(const short8*)(wkx_bf + (size_t)(wb + fm * 16 + lid) * 256 + kof);
    short8 av = *(const short8*)(wvsum_bf + (size_t)lid * 256 + kof);
#pragma unroll
    for (int fn = 0; fn < 8; ++fn) {
      short8 bb = frag_b(xl, fn * 16 + lid, kk, g);
#pragma unroll
      for (int fm = 0; fm < 4; ++fm)
        acc[fm][fn] = __builtin_amdgcn_mfma_f32_16x16x32_bf16(a[fm], bb, acc[fm][fn], 0, 0, 0);
    }
    // vsum mini-GEMM: this wave covers fn = 2*wave, 2*wave+1
#pragma unroll
    for (int fv = 0; fv < 2; ++fv) {
      short8 bb = frag_b(xl, (wave * 2 + fv) * 16 + lid, kk, g);
      vacc[fv] = __builtin_amdgcn_mfma_f32_16x16x32_bf16(av, bb, vacc[fv], 0, 0, 0);
    }
  }
  // scatter vsum rows 0..7 (g<2 holds rows g*4+r), col l = (wave*2+fv)*16+lid
  if (g < 2) {
#pragma unroll
    for (int fv = 0; fv < 2; ++fv)
#pragma unroll
      for (int r = 0; r < 4; ++r)
        vsum_lds[(g * 4 + r) * 128 + (wave * 2 + fv) * 16 + lid] = vacc[fv][r];
  }
  __syncthreads();

  float wky_r[4][4];
#pragma unroll
  for (int fm = 0; fm < 4; ++fm)
#pragma unroll
    for (int r = 0; r < 4; ++r) wky_r[fm][r] = wky_lds[wb + fm * 16 + g * 4 + r];

  float s1[4][4], s2[4][4];
#pragma unroll
  for (int fm = 0; fm < 4; ++fm)
#pragma unroll
    for (int r = 0; r < 4; ++r) { s1[fm][r] = 0.f; s2[fm][r] = 0.f; }

#pragma unroll
  for (int fn = 0; fn < 8; ++fn) {
    int l = fn * 16 + lid;
    float yv = yup_lds[l];
#pragma unroll
    for (int fm = 0; fm < 4; ++fm) {
      float vs = vsum_lds[(wave * 2 + (fm >> 1)) * 128 + l];   // head of c-rows
#pragma unroll
      for (int r = 0; r < 4; ++r) {
        float v = acc[fm][fn][r] * (wky_r[fm][r] * yv);
        float kq = v > 0.f ? v + 1.f : __expf(v);   // elu(v)+1
        s1[fm][r] += kq;
        s2[fm][r] += kq * vs;
      }
    }
  }
#pragma unroll
  for (int fm = 0; fm < 4; ++fm)
#pragma unroll
    for (int r = 0; r < 4; ++r) {
      float a1 = s1[fm][r], a2 = s2[fm][r];
#pragma unroll
      for (int off = 1; off < 16; off <<= 1) {
        a1 += __shfl_xor(a1, off);
        a2 += __shfl_xor(a2, off);
      }
      if (lid == 0) {
        int c = wb + fm * 16 + g * 4 + r;
        part[(size_t)bid * 512 + c]       = a1;
        part[(size_t)bid * 512 + 256 + c] = a2;
      }
    }
}

// ---------------- reduce partials -> ksum, kvs --------------------------------
__global__ __launch_bounds__(1024) void k_reduce(
    const float* __restrict__ part, float* __restrict__ ksum, float* __restrict__ kvs) {
  __shared__ float red[2][512];
  int b = blockIdx.x, tid = threadIdx.x;
  int u = tid & 511, h = tid >> 9;
  float s = 0.f;
  for (int j = 0; j < 64; ++j)
    s += part[(size_t)(b * NT + h * 64 + j) * 512 + u];
  red[h][u] = s;
  __syncthreads();
  if (tid < 512) {
    float t = red[0][tid] + red[1][tid];
    if (tid < 256) ksum[b * 256 + tid] = t;
    else           kvs[b * 256 + tid - 256] = t;
  }
}

// ---------------- pass 2: q, z, t, w_out GEMM, output -------------------------
__global__ __launch_bounds__(256, 2) void k_pass2(
    const float* __restrict__ x, const u16* __restrict__ wqx_bf,
    const u16* __restrict__ wout_bf, const float* __restrict__ wq_y,
    const float* __restrict__ yup, const float* __restrict__ ksum,
    const float* __restrict__ kvs, const float* __restrict__ b_out,
    float* __restrict__ out) {
  __shared__ u32x4 xbuf[4096];            // 64 KB
  __shared__ float yup_lds[128];
  __shared__ float wqy_lds[256];
  __shared__ float ksum_lds[256];
  __shared__ float kvs_lds[256];
  __shared__ float bout_lds[256];
  char* xl = (char*)xbuf;

  int tid = threadIdx.x, bid = blockIdx.x;
  int b = bid >> 7, tile = bid & 127;
  int l0 = tile * LT;

  if (tid < 128) yup_lds[tid] = yup[b * LDIM + l0 + tid];
  wqy_lds[tid]  = wq_y[tid];
  ksum_lds[tid] = ksum[b * 256 + tid];
  kvs_lds[tid]  = kvs[b * 256 + tid];
  bout_lds[tid] = b_out[tid];
  stage_x(xl, x, b, l0, tid);
  __syncthreads();

  int lane = tid & 63, wave = tid >> 6;
  int lid = lane & 15, g = lane >> 4;
  int wb = wave * 64;

  f32x4 z4 = {0.f, 0.f, 0.f, 0.f};
  f32x4 acc[4][8];
#pragma unroll
  for (int i = 0; i < 4; ++i)
#pragma unroll
    for (int j = 0; j < 8; ++j) acc[i][j] = z4;

  // GEMM1: q_x = wq_x * x
  for (int kk = 0; kk < 8; ++kk) {
    int kof = kk * 32 + g * 8;
    short8 a[4];
#pragma unroll
    for (int fm = 0; fm < 4; ++fm)
      a[fm] = *(const short8*)(wqx_bf + (size_t)(wb + fm * 16 + lid) * 256 + kof);
#pragma unroll
    for (int fn = 0; fn < 8; ++fn) {
      short8 bb = frag_b(xl, fn * 16 + lid, kk, g);
#pragma unroll
      for (int fm = 0; fm < 4; ++fm)
        acc[fm][fn] = __builtin_amdgcn_mfma_f32_16x16x32_bf16(a[fm], bb, acc[fm][fn], 0, 0, 0);
    }
  }
  __syncthreads();  // x_lds reads done; buffer reused for t

  float wqy_r[4][4], ks_r[4][4], kv_r[4][4];
#pragma unroll
  for (int fm = 0; fm < 4; ++fm)
#pragma unroll
    for (int r = 0; r < 4; ++r) {
      int c = wb + fm * 16 + g * 4 + r;
      wqy_r[fm][r] = wqy_lds[c];
      ks_r[fm][r]  = ksum_lds[c];
      kv_r[fm][r]  = kvs_lds[c];
    }

#pragma unroll
  for (int fn = 0; fn < 8; ++fn) {
    int l = fn * 16 + lid;
    float yv = yup_lds[l];
    float q[4][4];
    float d0 = 0.f, d1 = 0.f;
#pragma unroll
    for (int fm = 0; fm < 4; ++fm)
#pragma unroll
      for (int r = 0; r < 4; ++r) {
        float v = acc[fm][fn][r] * (wqy_r[fm][r] * yv);
        float qq = v > 0.f ? v + 1.f : __expf(v);   // elu(v)+1
        q[fm][r] = qq;
        if (fm < 2) d0 += qq * ks_r[fm][r]; else d1 += qq * ks_r[fm][r];
      }
    // lanes {lid,lid+16,lid+32,lid+48} share the same l -> head-sum over 32 c
    d0 += __shfl_xor(d0, 16); d0 += __shfl_xor(d0, 32);
    d1 += __shfl_xor(d1, 16); d1 += __shfl_xor(d1, 32);
    float zz0 = 1.f / (d0 + 1e-6f), zz1 = 1.f / (d1 + 1e-6f);
#pragma unroll
    for (int fm = 0; fm < 4; ++fm) {
      float zz = fm < 2 ? zz0 : zz1;
      ushort4v tw;
#pragma unroll
      for (int r = 0; r < 4; ++r) tw[r] = f2bf(q[fm][r] * kv_r[fm][r] * zz);
      int slot = (wave * 8 + fm * 2 + (g >> 1)) ^ swz(l);
      *(ushort4v*)(xl + (size_t)l * 512 + slot * 16 + (g & 1) * 8) = tw;
    }
  }
  __syncthreads();

  // GEMM2: out = w_out * t
#pragma unroll
  for (int i = 0; i < 4; ++i)
#pragma unroll
    for (int j = 0; j < 8; ++j) acc[i][j] = z4;
  for (int kk = 0; kk < 8; ++kk) {
    int kof = kk * 32 + g * 8;
    short8 a[4];
#pragma unroll
    for (int fm = 0; fm < 4; ++fm)
      a[fm] = *(const short8*)(wout_bf + (size_t)(wb + fm * 16 + lid) * 256 + kof);
#pragma unroll
    for (int fn = 0; fn < 8; ++fn) {
      short8 bb = frag_b(xl, fn * 16 + lid, kk, g);
#pragma unroll
      for (int fm = 0; fm < 4; ++fm)
        acc[fm][fn] = __builtin_amdgcn_mfma_f32_16x16x32_bf16(a[fm], bb, acc[fm][fn], 0, 0, 0);
    }
  }

  // epilogue
#pragma unroll
  for (int fm = 0; fm < 4; ++fm) {
#pragma unroll
    for (int r = 0; r < 4; ++r) {
      int o = wb + fm * 16 + g * 4 + r;
      float bo = bout_lds[o];
      size_t base = ((size_t)b * 256 + o) * LDIM + l0;
#pragma unroll
      for (int fn = 0; fn < 8; ++fn)
        out[base + fn * 16 + lid] = acc[fm][fn][r] + bo;
    }
  }
}

// ---------------- launch -------------------------------------------------------
extern "C" void kernel_launch(void* const* d_in, const int* in_sizes, int n_in,
                              void* d_out, int out_size, void* d_ws, size_t ws_size,
                              hipStream_t stream) {
  const float* x     = (const float*)d_in[0];
  const float* y     = (const float*)d_in[1];
  const float* wq_x  = (const float*)d_in[2];
  const float* wk_x  = (const float*)d_in[3];
  const float* wv    = (const float*)d_in[4];
  const float* wq_y  = (const float*)d_in[5];
  const float* wk_y  = (const float*)d_in[6];
  const float* w_out = (const float*)d_in[7];
  const float* b_out = (const float*)d_in[8];
  float* out = (float*)d_out;

  char* ws = (char*)d_ws;
  float* yup      = (float*)(ws + 0);         // 512 KB
  u16*   wqx_bf   = (u16*)(ws + 524288);      // 128 KB
  u16*   wkx_bf   = (u16*)(ws + 655360);      // 128 KB
  u16*   wout_bf  = (u16*)(ws + 786432);      // 128 KB
  u16*   wvsum_bf = (u16*)(ws + 917504);      // 8 KB
  float* ksum     = (float*)(ws + 925696);    // 8 KB
  float* kvs      = (float*)(ws + 933888);    // 8 KB
  float* part     = (float*)(ws + 942080);    // 2 MB

  k_prep<<<512, 256, 0, stream>>>(wq_x, wk_x, w_out, wv, y,
                                  wqx_bf, wkx_bf, wout_bf, wvsum_bf, yup);
  k_pass1<<<NB * NT, 256, 0, stream>>>(x, wkx_bf, wvsum_bf, wk_y, yup, part);
  k_reduce<<<NB, 1024, 0, stream>>>(part, ksum, kvs);
  k_pass2<<<NB * NT, 256, 0, stream>>>(x, wqx_bf, wout_bf, wq_y, yup,
                                       ksum, kvs, b_out, out);
}

// Round 5
// 152.181 us; speedup vs baseline: 1.7329x; 1.0053x over previous
//
#include <hip/hip_runtime.h>
#include <hip/hip_bf16.h>

typedef unsigned short u16;
typedef unsigned int   u32;
using short8   = __attribute__((ext_vector_type(8))) short;
using f32x4    = __attribute__((ext_vector_type(4))) float;
using ushort4v = __attribute__((ext_vector_type(4))) unsigned short;
using u32x4    = __attribute__((ext_vector_type(4))) unsigned int;

#define CDIM 256
#define LDIM 16384
#define LT   128
#define NT   128   // L tiles per batch
#define NB   8

__device__ __forceinline__ u16 f2bf(float f) {
  u32 u = __float_as_uint(f);
  u = (u + 0x7FFFu + ((u >> 16) & 1u)) >> 16;   // RTNE
  return (u16)u;
}

__device__ __forceinline__ u32 pk2(float a, float b) {
  __hip_bfloat162 h = __float22bfloat162_rn(make_float2(a, b));  // a -> low
  return *(u32*)&h;
}

// LDS image: byte(l,c) = l*512 + slot*16 + (c&7)*2,
//            slot = (c>>3) ^ swz(l),  swz(l) = ((l>>2)&31) ^ ((l&3)<<2)
__device__ __forceinline__ int swz(int l) {
  return ((l >> 2) & 31) ^ ((l & 3) << 2);
}

// B-fragment read: rows ll, k-slice = kk*32 + g*8 .. +7  (c-octet = kk*4+g)
__device__ __forceinline__ short8 frag_b(const char* xl, int ll, int kk, int g) {
  int slot = (kk * 4 + g) ^ swz(ll);
  return *(const short8*)(xl + (size_t)ll * 512 + slot * 16);
}

// ---------------- prep: weight bf16 conversion, wvsum, bilinear upsample ----
__global__ void k_prep(const float* __restrict__ wq_x, const float* __restrict__ wk_x,
                       const float* __restrict__ w_out, const float* __restrict__ wv,
                       const float* __restrict__ y,
                       u16* __restrict__ wqx_bf, u16* __restrict__ wkx_bf,
                       u16* __restrict__ wout_bf, u16* __restrict__ wvsum_bf,
                       float* __restrict__ yup) {
  int id = blockIdx.x * 256 + threadIdx.x;
  if (id < 65536) {
    wqx_bf[id]  = f2bf(wq_x[id]);
    wkx_bf[id]  = f2bf(wk_x[id]);
    wout_bf[id] = f2bf(w_out[id]);
  }
  if (id < 4096) {  // wvsum padded to 16 rows (rows 8..15 zero)
    int r = id >> 8, c = id & 255;
    float s = 0.f;
    if (r < 8) {
      for (int d2 = 0; d2 < 32; ++d2) s += wv[(r * 32 + d2) * 256 + c];
    }
    wvsum_bf[id] = f2bf(s);
  }
  if (id < 131072) {  // bilinear 2x upsample, half-pixel (align_corners=False)
    int b = id >> 14, rem = id & 16383, i = rem >> 7, j = rem & 127;
    float si = 0.5f * i - 0.25f, sj = 0.5f * j - 0.25f;
    int i0 = (int)floorf(si), j0 = (int)floorf(sj);
    float fi = si - (float)i0, fj = sj - (float)j0;
    int i0c = i0 < 0 ? 0 : i0, i1c = i0 + 1 > 63 ? 63 : i0 + 1;
    int j0c = j0 < 0 ? 0 : j0, j1c = j0 + 1 > 63 ? 63 : j0 + 1;
    const float* yb = y + b * 4096;
    float v = (1.f - fi) * ((1.f - fj) * yb[i0c * 64 + j0c] + fj * yb[i0c * 64 + j1c])
            +        fi  * ((1.f - fj) * yb[i1c * 64 + j0c] + fj * yb[i1c * 64 + j1c]);
    yup[id] = v;
  }
}

// ---------------- staging: x f32 -> swizzled LDS bf16 image, 256 threads -----
// lane k = tid&31 spans l contiguously -> each load inst covers 2x512B runs.
// LOWREG: limit live loads to one octet (8 float4 = 32 VGPR) for kernels whose
// register envelope is tight (pass2: 128 AGPR acc + 128 VGPR budget).
__device__ __forceinline__ void stage_one_octet(char* xl, const float* p, int so, int k) {
  float4 r0 = *(const float4*)(p + 0 * LDIM);
  float4 r1 = *(const float4*)(p + 1 * LDIM);
  float4 r2 = *(const float4*)(p + 2 * LDIM);
  float4 r3 = *(const float4*)(p + 3 * LDIM);
  float4 r4 = *(const float4*)(p + 4 * LDIM);
  float4 r5 = *(const float4*)(p + 5 * LDIM);
  float4 r6 = *(const float4*)(p + 6 * LDIM);
  float4 r7 = *(const float4*)(p + 7 * LDIM);
  const float* f0 = (const float*)&r0; const float* f1 = (const float*)&r1;
  const float* f2 = (const float*)&r2; const float* f3 = (const float*)&r3;
  const float* f4 = (const float*)&r4; const float* f5 = (const float*)&r5;
  const float* f6 = (const float*)&r6; const float* f7 = (const float*)&r7;
#pragma unroll
  for (int e = 0; e < 4; ++e) {
    int l = k * 4 + e;
    u32x4 wv;
    wv.x = pk2(f0[e], f1[e]);
    wv.y = pk2(f2[e], f3[e]);
    wv.z = pk2(f4[e], f5[e]);
    wv.w = pk2(f6[e], f7[e]);
    int slot = so ^ swz(l);
    *(u32x4*)(xl + (size_t)l * 512 + slot * 16) = wv;
  }
}

template<bool LOWREG>
__device__ __forceinline__ void stage_x(char* xl, const float* __restrict__ x,
                                        int b, int l0, int tid) {
  int k = tid & 31, co = tid >> 5;   // l-chunk (4 l's), base c-octet (0..7)
  const float* bp = x + ((size_t)b * 256 + co * 8) * LDIM + l0 + k * 4;
  if constexpr (LOWREG) {
#pragma unroll 1
    for (int oi = 0; oi < 4; ++oi)
      stage_one_octet(xl, bp + (size_t)(oi * 64) * LDIM, co + oi * 8, k);
  } else {
#pragma unroll
    for (int oi = 0; oi < 4; ++oi)
      stage_one_octet(xl, bp + (size_t)(oi * 64) * LDIM, co + oi * 8, k);
  }
}

// ---------------- pass 1: ksum / kvs partials ---------------------------------
__global__ __launch_bounds__(256, 2) void k_pass1(
    const float* __restrict__ x, const u16* __restrict__ wkx_bf,
    const u16* __restrict__ wvsum_bf, const float* __restrict__ wk_y,
    const float* __restrict__ yup, float* __restrict__ part) {
  __shared__ u32x4 xbuf[4096];            // 64 KB
  __shared__ float vsum_lds[8 * 128];     // [head][l]
  __shared__ float yup_lds[128];
  __shared__ float wky_lds[256];
  char* xl = (char*)xbuf;

  int tid = threadIdx.x, bid = blockIdx.x;
  int b = bid >> 7, tile = bid & 127;
  int l0 = tile * LT;

  if (tid < 128) yup_lds[tid] = yup[b * LDIM + l0 + tid];
  wky_lds[tid] = wk_y[tid];
  stage_x<false>(xl, x, b, l0, tid);
  __syncthreads();

  int lane = tid & 63, wave = tid >> 6;
  int lid = lane & 15, g = lane >> 4;
  int wb = wave * 64;

  f32x4 z4 = {0.f, 0.f, 0.f, 0.f};
  f32x4 acc[4][8];
#pragma unroll
  for (int i = 0; i < 4; ++i)
#pragma unroll
    for (int j = 0; j < 8; ++j) acc[i][j] = z4;
  f32x4 vacc[2] = {z4, z4};

  for (int kk = 0; kk < 8; ++kk) {
    int kof = kk * 32 + g * 8;
    short8 a[4];
#pragma unroll
    for (int fm = 0; fm < 4; ++fm)
      a[fm] = *(const short8*)(wkx_bf + (size_t)(wb + fm * 16 + lid) * 256 + kof);
    short8 av = *(const short8*)(wvsum_bf + (size_t)lid * 256 + kof);
#pragma unroll
    for (int fn = 0; fn < 8; ++fn) {
      short8 bb = frag_b(xl, fn * 16 + lid, kk, g);
#pragma unroll
      for (int fm = 0; fm < 4; ++fm)
        acc[fm][fn] = __builtin_amdgcn_mfma_f32_16x16x32_bf16(a[fm], bb, acc[fm][fn], 0, 0, 0);
    }
    // vsum mini-GEMM: this wave covers fn = 2*wave, 2*wave+1
#pragma unroll
    for (int fv = 0; fv < 2; ++fv) {
      short8 bb = frag_b(xl, (wave * 2 + fv) * 16 + lid, kk, g);
      vacc[fv] = __builtin_amdgcn_mfma_f32_16x16x32_bf16(av, bb, vacc[fv], 0, 0, 0);
    }
  }
  // scatter vsum rows 0..7 (g<2 holds rows g*4+r), col l = (wave*2+fv)*16+lid
  if (g < 2) {
#pragma unroll
    for (int fv = 0; fv < 2; ++fv)
#pragma unroll
      for (int r = 0; r < 4; ++r)
        vsum_lds[(g * 4 + r) * 128 + (wave * 2 + fv) * 16 + lid] = vacc[fv][r];
  }
  __syncthreads();

  float wky_r[4][4];
#pragma unroll
  for (int fm = 0; fm < 4; ++fm)
#pragma unroll
    for (int r = 0; r < 4; ++r) wky_r[fm][r] = wky_lds[wb + fm * 16 + g * 4 + r];

  float s1[4][4], s2[4][4];
#pragma unroll
  for (int fm = 0; fm < 4; ++fm)
#pragma unroll
    for (int r = 0; r < 4; ++r) { s1[fm][r] = 0.f; s2[fm][r] = 0.f; }

#pragma unroll
  for (int fn = 0; fn < 8; ++fn) {
    int l = fn * 16 + lid;
    float yv = yup_lds[l];
#pragma unroll
    for (int fm = 0; fm < 4; ++fm) {
      float vs = vsum_lds[(wave * 2 + (fm >> 1)) * 128 + l];   // head of c-rows
#pragma unroll
      for (int r = 0; r < 4; ++r) {
        float v = acc[fm][fn][r] * (wky_r[fm][r] * yv);
        float kq = v > 0.f ? v + 1.f : __expf(v);   // elu(v)+1
        s1[fm][r] += kq;
        s2[fm][r] += kq * vs;
      }
    }
  }
#pragma unroll
  for (int fm = 0; fm < 4; ++fm)
#pragma unroll
    for (int r = 0; r < 4; ++r) {
      float a1 = s1[fm][r], a2 = s2[fm][r];
#pragma unroll
      for (int off = 1; off < 16; off <<= 1) {
        a1 += __shfl_xor(a1, off);
        a2 += __shfl_xor(a2, off);
      }
      if (lid == 0) {
        int c = wb + fm * 16 + g * 4 + r;
        part[(size_t)bid * 512 + c]       = a1;
        part[(size_t)bid * 512 + 256 + c] = a2;
      }
    }
}

// ---------------- reduce partials -> ksum, kvs --------------------------------
__global__ __launch_bounds__(1024) void k_reduce(
    const float* __restrict__ part, float* __restrict__ ksum, float* __restrict__ kvs) {
  __shared__ float red[2][512];
  int b = blockIdx.x, tid = threadIdx.x;
  int u = tid & 511, h = tid >> 9;
  float s = 0.f;
  for (int j = 0; j < 64; ++j)
    s += part[(size_t)(b * NT + h * 64 + j) * 512 + u];
  red[h][u] = s;
  __syncthreads();
  if (tid < 512) {
    float t = red[0][tid] + red[1][tid];
    if (tid < 256) ksum[b * 256 + tid] = t;
    else           kvs[b * 256 + tid - 256] = t;
  }
}

// ---------------- pass 2: q, z, t, w_out GEMM, output -------------------------
__global__ __launch_bounds__(256, 2) void k_pass2(
    const float* __restrict__ x, const u16* __restrict__ wqx_bf,
    const u16* __restrict__ wout_bf, const float* __restrict__ wq_y,
    const float* __restrict__ yup, const float* __restrict__ ksum,
    const float* __restrict__ kvs, const float* __restrict__ b_out,
    float* __restrict__ out) {
  __shared__ u32x4 xbuf[4096];            // 64 KB
  __shared__ float yup_lds[128];
  __shared__ float wqy_lds[256];
  __shared__ float ksum_lds[256];
  __shared__ float kvs_lds[256];
  __shared__ float bout_lds[256];
  char* xl = (char*)xbuf;

  int tid = threadIdx.x, bid = blockIdx.x;
  int b = bid >> 7, tile = bid & 127;
  int l0 = tile * LT;

  if (tid < 128) yup_lds[tid] = yup[b * LDIM + l0 + tid];
  wqy_lds[tid]  = wq_y[tid];
  ksum_lds[tid] = ksum[b * 256 + tid];
  kvs_lds[tid]  = kvs[b * 256 + tid];
  bout_lds[tid] = b_out[tid];
  stage_x<true>(xl, x, b, l0, tid);
  __syncthreads();

  int lane = tid & 63, wave = tid >> 6;
  int lid = lane & 15, g = lane >> 4;
  int wb = wave * 64;

  f32x4 z4 = {0.f, 0.f, 0.f, 0.f};
  f32x4 acc[4][8];
#pragma unroll
  for (int i = 0; i < 4; ++i)
#pragma unroll
    for (int j = 0; j < 8; ++j) acc[i][j] = z4;

  // GEMM1: q_x = wq_x * x
  for (int kk = 0; kk < 8; ++kk) {
    int kof = kk * 32 + g * 8;
    short8 a[4];
#pragma unroll
    for (int fm = 0; fm < 4; ++fm)
      a[fm] = *(const short8*)(wqx_bf + (size_t)(wb + fm * 16 + lid) * 256 + kof);
#pragma unroll
    for (int fn = 0; fn < 8; ++fn) {
      short8 bb = frag_b(xl, fn * 16 + lid, kk, g);
#pragma unroll
      for (int fm = 0; fm < 4; ++fm)
        acc[fm][fn] = __builtin_amdgcn_mfma_f32_16x16x32_bf16(a[fm], bb, acc[fm][fn], 0, 0, 0);
    }
  }
  __syncthreads();  // x_lds reads done; buffer reused for t

  float wqy_r[4][4], ks_r[4][4], kv_r[4][4];
#pragma unroll
  for (int fm = 0; fm < 4; ++fm)
#pragma unroll
    for (int r = 0; r < 4; ++r) {
      int c = wb + fm * 16 + g * 4 + r;
      wqy_r[fm][r] = wqy_lds[c];
      ks_r[fm][r]  = ksum_lds[c];
      kv_r[fm][r]  = kvs_lds[c];
    }

#pragma unroll
  for (int fn = 0; fn < 8; ++fn) {
    int l = fn * 16 + lid;
    float yv = yup_lds[l];
    float q[4][4];
    float d0 = 0.f, d1 = 0.f;
#pragma unroll
    for (int fm = 0; fm < 4; ++fm)
#pragma unroll
      for (int r = 0; r < 4; ++r) {
        float v = acc[fm][fn][r] * (wqy_r[fm][r] * yv);
        float qq = v > 0.f ? v + 1.f : __expf(v);   // elu(v)+1
        q[fm][r] = qq;
        if (fm < 2) d0 += qq * ks_r[fm][r]; else d1 += qq * ks_r[fm][r];
      }
    // lanes {lid,lid+16,lid+32,lid+48} share the same l -> head-sum over 32 c
    d0 += __shfl_xor(d0, 16); d0 += __shfl_xor(d0, 32);
    d1 += __shfl_xor(d1, 16); d1 += __shfl_xor(d1, 32);
    float zz0 = 1.f / (d0 + 1e-6f), zz1 = 1.f / (d1 + 1e-6f);
#pragma unroll
    for (int fm = 0; fm < 4; ++fm) {
      float zz = fm < 2 ? zz0 : zz1;
      ushort4v tw;
#pragma unroll
      for (int r = 0; r < 4; ++r) tw[r] = f2bf(q[fm][r] * kv_r[fm][r] * zz);
      int slot = (wave * 8 + fm * 2 + (g >> 1)) ^ swz(l);
      *(ushort4v*)(xl + (size_t)l * 512 + slot * 16 + (g & 1) * 8) = tw;
    }
  }
  __syncthreads();

  // GEMM2: out = w_out * t
#pragma unroll
  for (int i = 0; i < 4; ++i)
#pragma unroll
    for (int j = 0; j < 8; ++j) acc[i][j] = z4;
  for (int kk = 0; kk < 8; ++kk) {
    int kof = kk * 32 + g * 8;
    short8 a[4];
#pragma unroll
    for (int fm = 0; fm < 4; ++fm)
      a[fm] = *(const short8*)(wout_bf + (size_t)(wb + fm * 16 + lid) * 256 + kof);
#pragma unroll
    for (int fn = 0; fn < 8; ++fn) {
      short8 bb = frag_b(xl, fn * 16 + lid, kk, g);
#pragma unroll
      for (int fm = 0; fm < 4; ++fm)
        acc[fm][fn] = __builtin_amdgcn_mfma_f32_16x16x32_bf16(a[fm], bb, acc[fm][fn], 0, 0, 0);
    }
  }

  // epilogue
#pragma unroll
  for (int fm = 0; fm < 4; ++fm) {
#pragma unroll
    for (int r = 0; r < 4; ++r) {
      int o = wb + fm * 16 + g * 4 + r;
      float bo = bout_lds[o];
      size_t base = ((size_t)b * 256 + o) * LDIM + l0;
#pragma unroll
      for (int fn = 0; fn < 8; ++fn)
        out[base + fn * 16 + lid] = acc[fm][fn][r] + bo;
    }
  }
}

// ---------------- launch -------------------------------------------------------
extern "C" void kernel_launch(void* const* d_in, const int* in_sizes, int n_in,
                              void* d_out, int out_size, void* d_ws, size_t ws_size,
                              hipStream_t stream) {
  const float* x     = (const float*)d_in[0];
  const float* y     = (const float*)d_in[1];
  const float* wq_x  = (const float*)d_in[2];
  const float* wk_x  = (const float*)d_in[3];
  const float* wv    = (const float*)d_in[4];
  const float* wq_y  = (const float*)d_in[5];
  const float* wk_y  = (const float*)d_in[6];
  const float* w_out = (const float*)d_in[7];
  const float* b_out = (const float*)d_in[8];
  float* out = (float*)d_out;

  char* ws = (char*)d_ws;
  float* yup      = (float*)(ws + 0);         // 512 KB
  u16*   wqx_bf   = (u16*)(ws + 524288);      // 128 KB
  u16*   wkx_bf   = (u16*)(ws + 655360);      // 128 KB
  u16*   wout_bf  = (u16*)(ws + 786432);      // 128 KB
  u16*   wvsum_bf = (u16*)(ws + 917504);      // 8 KB
  float* ksum     = (float*)(ws + 925696);    // 8 KB
  float* kvs      = (float*)(ws + 933888);    // 8 KB
  float* part     = (float*)(ws + 942080);    // 2 MB

  k_prep<<<512, 256, 0, stream>>>(wq_x, wk_x, w_out, wv, y,
                                  wqx_bf, wkx_bf, wout_bf, wvsum_bf, yup);
  k_pass1<<<NB * NT, 256, 0, stream>>>(x, wkx_bf, wvsum_bf, wk_y, yup, part);
  k_reduce<<<NB, 1024, 0, stream>>>(part, ksum, kvs);
  k_pass2<<<NB * NT, 256, 0, stream>>>(x, wqx_bf, wout_bf, wq_y, yup,
                                       ksum, kvs, b_out, out);
}